// Round 14
// baseline (151.136 us; speedup 1.0000x reference)
//
#include <hip/hip_runtime.h>
#include <cmath>

#define TWO_PI 6.283185307179586476925f

typedef float f2 __attribute__((ext_vector_type(2)));

__device__ __forceinline__ float sigm(float v) { return 1.0f / (1.0f + __expf(-v)); }
__device__ __forceinline__ f2 mnegi(f2 v) { return (f2){v.y, -v.x}; }   // v * (-i)
__device__ __forceinline__ f2 mposi(f2 v) { return (f2){-v.y, v.x}; }   // v * (+i)
__device__ __forceinline__ f2 cmulf(f2 a, f2 b) {
    return (f2){a.x, a.x} * b + (f2){a.y, a.y} * mposi(b);
}
// complex multiply by constant A
__device__ __forceinline__ f2 cms(f2 A, f2 v) {
    return (f2){A.x, A.x} * v + (f2){A.y, A.y} * (f2){-v.y, v.x};
}

// DPP lane move within 16-lane rows; invalid sources read 0 (bound_ctrl).
template<int CTRL>
__device__ __forceinline__ float dpp0(float v) {
    return __int_as_float(__builtin_amdgcn_update_dpp(
        0, __float_as_int(v), CTRL, 0xf, 0xf, true));
}
template<int CTRL>
__device__ __forceinline__ f2 dpp2(f2 v) {
    return (f2){dpp0<CTRL>(v.x), dpp0<CTRL>(v.y)};
}
#define DPP_SHR1 0x111
#define DPP_SHR2 0x112
#define DPP_SHR4 0x114
#define DPP_ROR8 0x128

__device__ __forceinline__ float swz_xor16(float v) {
    return __int_as_float(__builtin_amdgcn_ds_swizzle(__float_as_int(v), 0x401F));
}

// XOR-swizzled cell address for a 64x64 f2 tile.
__device__ __forceinline__ int swz(int r, int c) {
    return (r << 6) | (c ^ ((r ^ (r << 3)) & 63));
}

// Gf layout: element (freq row u = o+8m, freq col c) at (c<<6)|(o<<3)|m.
__device__ __forceinline__ int gfx2(int o, int m, int c) {
    return (c << 6) | (o << 3) | m;
}

// In-register 8-point DFT. INV: conj twiddles. HALF: x[4..7] zero. PRUNE: skip x[4..7] outs.
template<bool INV, bool HALF, bool PRUNE>
__device__ __forceinline__ void dft8(f2* x) {
    const float RS = 0.70710678118654752440f;
    f2 t0, t1, t2, t3, t4, t5, t6, t7;
    if (HALF) {
        t0 = x[0]; t4 = x[0]; t1 = x[1]; t5 = x[1];
        t2 = x[2]; t6 = x[2]; t3 = x[3]; t7 = x[3];
    } else {
        t0 = x[0] + x[4]; t4 = x[0] - x[4];
        t1 = x[1] + x[5]; t5 = x[1] - x[5];
        t2 = x[2] + x[6]; t6 = x[2] - x[6];
        t3 = x[3] + x[7]; t7 = x[3] - x[7];
    }
    f2 t5w, t6w, t7w;
    if (!INV) {
        t5w = RS * (t5 + mnegi(t5));
        t6w = mnegi(t6);
        t7w = RS * (mnegi(t7) - t7);
    } else {
        t5w = RS * (t5 - mnegi(t5));
        t6w = mposi(t6);
        t7w = RS * (mposi(t7) - t7);
    }
    f2 u0 = t0 + t2, u2 = t0 - t2, u1 = t1 + t3, dd = t1 - t3;
    f2 u3 = INV ? mposi(dd) : mnegi(dd);
    x[0] = u0 + u1; x[2] = u2 + u3;
    if (!PRUNE) { x[4] = u0 - u1; x[6] = u2 - u3; }
    f2 v0 = t4 + t6w, v2 = t4 - t6w, v1 = t5w + t7w, ee = t5w - t7w;
    f2 v3 = INV ? mposi(ee) : mnegi(ee);
    x[1] = v0 + v1; x[3] = v2 + v3;
    if (!PRUNE) { x[5] = v0 - v1; x[7] = v2 - v3; }
}

__device__ __forceinline__ void make_tw(int o, f2* tw) {
    float s, co;
    __sincosf(-TWO_PI * (float)o / 64.f, &s, &co);
    tw[0] = (f2){co, s};
#pragma unroll
    for (int k = 1; k < 7; ++k) tw[k] = cmulf(tw[k - 1], tw[0]);
}

// 64-pt FFT over one line by an 8-lane group. In: reg j = point (8j+o).
// Out: reg m = point (o+8m) (PRUNE: only m<4 valid). Natural order.
template<bool INV, bool COL, bool HALF, bool PRUNE>
__device__ __forceinline__ void fft64(f2* a, f2* r, const f2* tw,
                                      int o, int line) {
    dft8<INV, HALF, false>(r);
#pragma unroll
    for (int k = 1; k < 8; ++k) {
        f2 w = tw[k - 1];
        if (INV) w.y = -w.y;
        r[k] = cmulf(r[k], w);
    }
#pragma unroll
    for (int m = 0; m < 8; ++m) {
        int s = 8 * o + m;
        a[COL ? swz(s, line) : swz(line, s)] = r[m];
    }
#pragma unroll
    for (int j = 0; j < 8; ++j) {
        int s = 8 * j + o;
        r[j] = a[COL ? swz(s, line) : swz(line, s)];
    }
    dft8<INV, false, PRUNE>(r);
}

// ---------------- P1: fused SSM+spectrum (blocks <768) + input transpose ------
__global__ __launch_bounds__(512) void ssm_tin(
        const float* __restrict__ Aang, const float* __restrict__ Arad,
        const float* __restrict__ B1p, const float* __restrict__ B2p,
        const float* __restrict__ C1p, const float* __restrict__ C2p,
        f2* __restrict__ Gf, const float* __restrict__ x,
        float* __restrict__ xT) {
    __shared__ __align__(16) char smem[35840];
    int tid = threadIdx.x;

    if (blockIdx.x >= 768) {
        // ---- input transpose path (float4 global sides) ----
        float (*tt)[65] = (float (*)[65])smem;
        int bb = blockIdx.x - 768;
        int bR = bb % 192, bS = bb / 192;
        int r0 = bR * 64, s0 = bS * 64;
        int c4 = (tid & 15) * 4, rw = tid >> 4;   // rw 0..31
#pragma unroll
        for (int k = 0; k < 2; ++k) {
            int row = rw + 32 * k;
            float4 v = *(const float4*)&x[(size_t)(s0 + row) * 12288 + r0 + c4];
            tt[row][c4] = v.x; tt[row][c4 + 1] = v.y;
            tt[row][c4 + 2] = v.z; tt[row][c4 + 3] = v.w;
        }
        __syncthreads();
#pragma unroll
        for (int k = 0; k < 2; ++k) {
            int row = rw + 32 * k;
            float4 v = {tt[c4][row], tt[c4 + 1][row], tt[c4 + 2][row], tt[c4 + 3][row]};
            *(float4*)&xT[(size_t)(r0 + row) * 1024 + s0 + c4] = v;
        }
        return;
    }

    f2* a = (f2*)smem;                          // 32768 B
    float* row0 = (float*)(smem + 32768);       // [t][nh][c]  2048 B
    float* col0 = (float*)(smem + 34816);       // [t>>1][nh][r] 1024 B
    int d = blockIdx.x;
    int w = tid >> 6;
    int t = w & 3;
    int nh = w >> 2;
    int lane = tid & 63;
    int jg = lane & 7;
    int n8 = lane >> 3;
    int n = n8 + 8 * nh;
    int ch = t * 768 + d;
    int gid = ch * 16 + n;

    for (int e = tid; e < 4096; e += 512) a[e] = (f2){0.f, 0.f};
    row0[tid] = 0.f;
    if (tid < 256) col0[tid] = 0.f;

    f2 A[4];
#pragma unroll
    for (int q = 0; q < 4; ++q) {
        float ang = sigm(Aang[q * 49152 + gid]) * TWO_PI;
        float rad = sigm(Arad[q * 49152 + gid]);
        float s, co;
        __sincosf(ang, &s, &co);
        A[q] = (f2){rad * co, rad * s};
    }
    f2 A1 = A[0], A2 = A[1], A3 = A[2], A4 = A[3];
    f2 P2 = cms(A1, A1);
    f2 P3 = cms(A1, P2);
    f2 P4 = cms(P2, P2);
    f2 P8 = cms(P4, P4);
    f2 P16 = cms(P8, P8);
    f2 CZ1 = (jg >= 1) ? P4 : (f2){0.f, 0.f};
    f2 CZ2 = (jg >= 2) ? P8 : (f2){0.f, 0.f};
    f2 CZ4 = (jg >= 4) ? P16 : (f2){0.f, 0.f};

    const float2* B1v = (const float2*)B1p;
    const float2* B2v = (const float2*)B2p;
    const float2* C1v = (const float2*)C1p;
    const float2* C2v = (const float2*)C2p;
    float2 b1 = B1v[gid], b2 = B2v[gid], c1 = C1v[gid], c2 = C2v[gid];
    f2 B1 = (f2){sigm(b1.x), sigm(b1.y)};
    f2 B2 = (f2){sigm(b2.x), sigm(b2.y)};
    f2 C1n = (f2){c1.x, -c1.y};
    f2 C2n = (f2){c2.x, -c2.y};

    // EB = A1^{4*jg} * B1
    f2 pw = (f2){1.f, 0.f};
    if (jg & 1) pw = P4;
    if (jg & 2) pw = cms(pw, P8);
    if (jg & 4) pw = cms(pw, P16);
    f2 EB = cms(pw, B1);

    int bb0 = n8 & 1, bb1 = (n8 >> 1) & 1;
    int col = 4 * jg + 2 * bb0 + bb1;
    int ccl = (t & 2) ? ((64 - col) & 63) : col;

    __syncthreads();

    f2 xv[4], xh[4];
#pragma unroll
    for (int m = 0; m < 4; ++m) { xv[m] = (f2){0.f, 0.f}; xh[m] = (f2){0.f, 0.f}; }

    auto body = [&](int i, bool is0) {
#pragma unroll
        for (int m = 0; m < 4; ++m) xv[m] = cms(A3, xh[m]) + cms(A4, xv[m]);
        if (is0 && jg == 0) xv[0] += B2;
        f2 g1 = cms(A2, xv[0]);
        f2 g2 = cms(A1, g1) + cms(A2, xv[1]);
        f2 g3 = cms(A1, g2) + cms(A2, xv[2]);
        f2 V  = cms(A1, g3) + cms(A2, xv[3]);
        V += cms(CZ1, dpp2<DPP_SHR1>(V));
        V += cms(CZ2, dpp2<DPP_SHR2>(V));
        V += cms(CZ4, dpp2<DPP_SHR4>(V));
        f2 E = dpp2<DPP_SHR1>(V);
        if (jg == 0) E = (f2){0.f, 0.f};
        if (is0) E += EB;
        xh[0] = E;
        xh[1] = cms(A1, E) + g1;
        xh[2] = cms(P2, E) + g2;
        xh[3] = cms(P3, E) + g3;
        f2 d0 = C1n * xh[0] + C2n * xv[0];
        f2 d1 = C1n * xh[1] + C2n * xv[1];
        f2 d2 = C1n * xh[2] + C2n * xv[2];
        f2 d3 = C1n * xh[3] + C2n * xv[3];
        float v0 = d0.x + d0.y, v1 = d1.x + d1.y;
        float v2 = d2.x + d2.y, v3 = d3.x + d3.y;
        float s0 = bb0 ? v0 : v2, s1 = bb0 ? v1 : v3;
        float r0 = dpp0<DPP_ROR8>(s0), r1 = dpp0<DPP_ROR8>(s1);
        float q0 = (bb0 ? v2 : v0) + r0;
        float q1 = (bb0 ? v3 : v1) + r1;
        float s2 = bb1 ? q0 : q1;
        float r2 = swz_xor16(s2);
        float qq = (bb1 ? q1 : q0) + r2;
        qq += __shfl_xor(qq, 32, 64);
        if (n8 < 4) {
            if (is0) {
                row0[(((t << 1) | nh) << 6) | ccl] = qq;
            } else if (col == 0) {
                col0[((((t >> 1) << 1) | nh) << 6) | ((t & 1) ? (64 - i) : i)] = qq;
            } else {
                int rr_ = (t & 1) ? (64 - i) : i;
                ((float*)&a[swz(rr_, ccl)])[nh] = qq;
            }
        }
    };
    body(0, true);
#pragma unroll 2
    for (int i = 1; i < 32; ++i) body(i, false);

    __syncthreads();
    // fold: combine nh components + edge buffers, apply boundary factors
    for (int e = tid; e < 4096; e += 512) {
        int r = e >> 6, cm = e & 63;
        int c = cm ^ ((r ^ (r << 3)) & 63);
        f2 cv = a[e];
        float v = cv.x + cv.y;
        if (r == 0) {
            v += row0[c] + row0[64 + c] + row0[128 + c] + row0[192 + c]
               + row0[256 + c] + row0[320 + c] + row0[384 + c] + row0[448 + c];
        } else if (c == 0) {
            v += col0[r] + col0[64 + r] + col0[128 + r] + col0[192 + r];
        }
        float f = 0.25f;
        if (r == 0) f *= 2.f;
        if (c == 0) f *= 2.f;
        if (r == 0 && c == 0) f *= 0.25f;
        a[e] = (f2){f * v, 0.f};
    }
    __syncthreads();
    // 2D forward FFT -> Gf (single sweeps, 64 groups)
    int o = tid & 7;
    f2 tw[7];
    make_tw(o, tw);
    {
        int row = tid >> 3;
        f2 r[8];
#pragma unroll
        for (int j = 0; j < 8; ++j) r[j] = a[swz(row, 8 * j + o)];
        fft64<false, false, false, false>(a, r, tw, o, row);
#pragma unroll
        for (int m = 0; m < 8; ++m) a[swz(row, o + 8 * m)] = r[m];
    }
    __syncthreads();
    {
        int cc = tid >> 3;
        f2 r[8];
#pragma unroll
        for (int j = 0; j < 8; ++j) r[j] = a[swz(8 * j + o, cc)];
        fft64<false, true, false, false>(a, r, tw, o, cc);
        f2* GfD = Gf + d * 4096;
#pragma unroll
        for (int m = 0; m < 8; ++m) GfD[gfx2(o, m, cc)] = r[m];   // 64B contiguous
    }
}

// ---------------- P3: FFT conv, one b-pair tile, 256 thr (no idle phases) -----
// 32 groups: row phases use all groups (32 rows); col phase = 2 full sweeps.
// xsave: epilogue x values == prologue values (cols 8j+o == o+8m) -> no re-read.
__global__ __launch_bounds__(256) void conv_fft(
        const float* __restrict__ x, float* __restrict__ xT,
        const f2* __restrict__ Gf, const float* __restrict__ omega,
        float* __restrict__ out, int useT) {
    __shared__ f2 a[4096];
    // XCD-chunked swizzle: same-d blocks (8 bpairs) colocate on one XCD.
    int bid = (blockIdx.x & 7) * 768 + (blockIdx.x >> 3);
    int d = bid >> 3, b = (bid & 7) * 2;
    int tid = threadIdx.x;
    int o = tid & 7, grp = tid >> 3;      // grp 0..31
    f2 tw[7];
    make_tw(o, tw);
    const size_t base0 = (size_t)(b * 768 + d) * 1024;
    const size_t base1 = (size_t)((b + 1) * 768 + d) * 1024;
    f2 xsave[4];
    // ---- forward rows: 32 groups x 32 rows, all busy ----
    {
        int row = grp;
        f2 r[8];
#pragma unroll
        for (int j = 0; j < 4; ++j) {
            int s2 = row * 32 + 8 * j + o;
            if (useT) r[j] = (f2){xT[base0 + s2], xT[base1 + s2]};
            else      r[j] = (f2){x[s2 * 12288 + b * 768 + d],
                                  x[s2 * 12288 + (b + 1) * 768 + d]};
            xsave[j] = r[j];
        }
#pragma unroll
        for (int j = 4; j < 8; ++j) r[j] = (f2){0.f, 0.f};
        fft64<false, false, true, false>(a, r, tw, o, row);
#pragma unroll
        for (int m = 0; m < 8; ++m) a[swz(row, o + 8 * m)] = r[m];
    }
    __syncthreads();
    // ---- columns: 2 sweeps x 32 cols, all busy; fwd ⊙ Gf, inv in registers ----
    const f2* GfD = Gf + d * 4096;
#pragma unroll 1
    for (int sw = 0; sw < 2; ++sw) {
        int c = sw * 32 + grp;
        f2 r[8];
#pragma unroll
        for (int j = 0; j < 4; ++j) r[j] = a[swz(8 * j + o, c)];
#pragma unroll
        for (int j = 4; j < 8; ++j) r[j] = (f2){0.f, 0.f};
        fft64<false, true, true, false>(a, r, tw, o, c);
#pragma unroll
        for (int m = 0; m < 8; ++m) {
            r[m] = cmulf(r[m], GfD[gfx2(o, m, c)]);   // 64B contiguous/thread
        }
        fft64<true, true, false, true>(a, r, tw, o, c);
#pragma unroll
        for (int m = 0; m < 4; ++m) a[swz(o + 8 * m, c)] = r[m];
    }
    __syncthreads();
    // ---- inverse rows + epilogue: 32 groups x 32 rows ----
    {
        int row = grp;
        f2 r[8];
#pragma unroll
        for (int j = 0; j < 8; ++j) r[j] = a[swz(row, 8 * j + o)];
        fft64<true, false, false, true>(a, r, tw, o, row);
        float w = omega[d];
        const float inv = 1.0f / 4096.0f;
#pragma unroll
        for (int m = 0; m < 4; ++m) {
            int cc = o + 8 * m;
            int s2 = row * 32 + cc;
            float xa = xsave[m].x, xb = xsave[m].y;   // cols 8m+o == o+8m
            float ya = r[m].x * inv + xa * w;
            float yb = r[m].y * inv + xb * w;
            float oa = ya / (1.0f + __expf(-ya));
            float ob = yb / (1.0f + __expf(-yb));
            if (useT) {
                xT[base0 + s2] = oa;        // overwrite own row (outT alias)
                xT[base1 + s2] = ob;
            } else {
                out[s2 * 12288 + b * 768 + d] = oa;
                out[s2 * 12288 + (b + 1) * 768 + d] = ob;
            }
        }
    }
}

// ---------------- P4: xT (BD,S) -> out (S,BD), 64x64 tiles, float4 ------------
__global__ __launch_bounds__(256) void transpose_out(const float* __restrict__ xT,
                                                     float* __restrict__ out) {
    __shared__ float t[64][65];
    int bR = blockIdx.x % 192, bS = blockIdx.x / 192;
    int r0 = bR * 64, s0 = bS * 64;
    int c4 = (threadIdx.x & 15) * 4, rw = threadIdx.x >> 4;   // rw 0..15
#pragma unroll
    for (int k = 0; k < 4; ++k) {
        int row = rw + 16 * k;
        float4 v = *(const float4*)&xT[(size_t)(r0 + row) * 1024 + s0 + c4];
        t[row][c4] = v.x; t[row][c4 + 1] = v.y;
        t[row][c4 + 2] = v.z; t[row][c4 + 3] = v.w;
    }
    __syncthreads();
#pragma unroll
    for (int k = 0; k < 4; ++k) {
        int row = rw + 16 * k;
        float4 v = {t[c4][row], t[c4 + 1][row], t[c4 + 2][row], t[c4 + 3][row]};
        *(float4*)&out[(size_t)(s0 + row) * 12288 + r0 + c4] = v;
    }
}

extern "C" void kernel_launch(void* const* d_in, const int* in_sizes, int n_in,
                              void* d_out, int out_size, void* d_ws, size_t ws_size,
                              hipStream_t stream) {
    const float* x     = (const float*)d_in[0];
    const float* Aang  = (const float*)d_in[1];
    const float* Arad  = (const float*)d_in[2];
    const float* B1p   = (const float*)d_in[3];
    const float* B2p   = (const float*)d_in[4];
    const float* C1p   = (const float*)d_in[5];
    const float* C2p   = (const float*)d_in[6];
    const float* omega = (const float*)d_in[7];
    float* out = (float*)d_out;
    char* ws = (char*)d_ws;

    f2*    Gf = (f2*)ws;                            // 25,165,824 B
    float* xT = (float*)(ws + 25165824);            // 50,331,648 B (in+out alias)
    int useT = (ws_size >= (size_t)75497472) ? 1 : 0;

    int grid1 = useT ? 3840 : 768;   // 768 ssm blocks + 3072 transpose blocks
    ssm_tin<<<grid1, 512, 0, stream>>>(Aang, Arad, B1p, B2p, C1p, C2p, Gf, x, xT);
    conv_fft<<<6144, 256, 0, stream>>>(x, xT, Gf, omega, out, useT);
    if (useT) transpose_out<<<3072, 256, 0, stream>>>(xT, out);
}

// Round 15
// 143.379 us; speedup vs baseline: 1.0541x; 1.0541x over previous
//
#include <hip/hip_runtime.h>
#include <cmath>

#define TWO_PI 6.283185307179586476925f

typedef float f2 __attribute__((ext_vector_type(2)));

__device__ __forceinline__ float sigm(float v) { return 1.0f / (1.0f + __expf(-v)); }
__device__ __forceinline__ f2 mnegi(f2 v) { return (f2){v.y, -v.x}; }   // v * (-i)
__device__ __forceinline__ f2 mposi(f2 v) { return (f2){-v.y, v.x}; }   // v * (+i)
__device__ __forceinline__ f2 cmulf(f2 a, f2 b) {
    return (f2){a.x, a.x} * b + (f2){a.y, a.y} * mposi(b);
}
// complex multiply by constant A
__device__ __forceinline__ f2 cms(f2 A, f2 v) {
    return (f2){A.x, A.x} * v + (f2){A.y, A.y} * (f2){-v.y, v.x};
}

// DPP lane move within 16-lane rows; invalid sources read 0 (bound_ctrl).
template<int CTRL>
__device__ __forceinline__ float dpp0(float v) {
    return __int_as_float(__builtin_amdgcn_update_dpp(
        0, __float_as_int(v), CTRL, 0xf, 0xf, true));
}
template<int CTRL>
__device__ __forceinline__ f2 dpp2(f2 v) {
    return (f2){dpp0<CTRL>(v.x), dpp0<CTRL>(v.y)};
}
#define DPP_SHR1 0x111
#define DPP_SHR2 0x112
#define DPP_SHR4 0x114
#define DPP_ROR8 0x128

__device__ __forceinline__ float swz_xor16(float v) {
    return __int_as_float(__builtin_amdgcn_ds_swizzle(__float_as_int(v), 0x401F));
}

// XOR-swizzled cell address for a 64x64 f2 tile.
__device__ __forceinline__ int swz(int r, int c) {
    return (r << 6) | (c ^ ((r ^ (r << 3)) & 63));
}

// Gf layout: element (freq row u = o+8m, freq col c) at (c<<6)|(o<<3)|m.
__device__ __forceinline__ int gfx2(int o, int m, int c) {
    return (c << 6) | (o << 3) | m;
}

// In-register 8-point DFT. INV: conj twiddles. HALF: x[4..7] zero. PRUNE: skip x[4..7] outs.
template<bool INV, bool HALF, bool PRUNE>
__device__ __forceinline__ void dft8(f2* x) {
    const float RS = 0.70710678118654752440f;
    f2 t0, t1, t2, t3, t4, t5, t6, t7;
    if (HALF) {
        t0 = x[0]; t4 = x[0]; t1 = x[1]; t5 = x[1];
        t2 = x[2]; t6 = x[2]; t3 = x[3]; t7 = x[3];
    } else {
        t0 = x[0] + x[4]; t4 = x[0] - x[4];
        t1 = x[1] + x[5]; t5 = x[1] - x[5];
        t2 = x[2] + x[6]; t6 = x[2] - x[6];
        t3 = x[3] + x[7]; t7 = x[3] - x[7];
    }
    f2 t5w, t6w, t7w;
    if (!INV) {
        t5w = RS * (t5 + mnegi(t5));
        t6w = mnegi(t6);
        t7w = RS * (mnegi(t7) - t7);
    } else {
        t5w = RS * (t5 - mnegi(t5));
        t6w = mposi(t6);
        t7w = RS * (mposi(t7) - t7);
    }
    f2 u0 = t0 + t2, u2 = t0 - t2, u1 = t1 + t3, dd = t1 - t3;
    f2 u3 = INV ? mposi(dd) : mnegi(dd);
    x[0] = u0 + u1; x[2] = u2 + u3;
    if (!PRUNE) { x[4] = u0 - u1; x[6] = u2 - u3; }
    f2 v0 = t4 + t6w, v2 = t4 - t6w, v1 = t5w + t7w, ee = t5w - t7w;
    f2 v3 = INV ? mposi(ee) : mnegi(ee);
    x[1] = v0 + v1; x[3] = v2 + v3;
    if (!PRUNE) { x[5] = v0 - v1; x[7] = v2 - v3; }
}

__device__ __forceinline__ void make_tw(int o, f2* tw) {
    float s, co;
    __sincosf(-TWO_PI * (float)o / 64.f, &s, &co);
    tw[0] = (f2){co, s};
#pragma unroll
    for (int k = 1; k < 7; ++k) tw[k] = cmulf(tw[k - 1], tw[0]);
}

// 64-pt FFT over one line by an 8-lane group. In: reg j = point (8j+o).
// Out: reg m = point (o+8m) (PRUNE: only m<4 valid). Natural order.
template<bool INV, bool COL, bool HALF, bool PRUNE>
__device__ __forceinline__ void fft64(f2* a, f2* r, const f2* tw,
                                      int o, int line) {
    dft8<INV, HALF, false>(r);
#pragma unroll
    for (int k = 1; k < 8; ++k) {
        f2 w = tw[k - 1];
        if (INV) w.y = -w.y;
        r[k] = cmulf(r[k], w);
    }
#pragma unroll
    for (int m = 0; m < 8; ++m) {
        int s = 8 * o + m;
        a[COL ? swz(s, line) : swz(line, s)] = r[m];
    }
#pragma unroll
    for (int j = 0; j < 8; ++j) {
        int s = 8 * j + o;
        r[j] = a[COL ? swz(s, line) : swz(line, s)];
    }
    dft8<INV, false, PRUNE>(r);
}

// ---------------- P1: fused SSM+spectrum (blocks <768) + input transpose ------
__global__ __launch_bounds__(512) void ssm_tin(
        const float* __restrict__ Aang, const float* __restrict__ Arad,
        const float* __restrict__ B1p, const float* __restrict__ B2p,
        const float* __restrict__ C1p, const float* __restrict__ C2p,
        f2* __restrict__ Gf, const float* __restrict__ x,
        float* __restrict__ xT) {
    __shared__ __align__(16) char smem[35840];
    int tid = threadIdx.x;

    if (blockIdx.x >= 768) {
        // ---- input transpose path (float4 global sides) ----
        float (*tt)[65] = (float (*)[65])smem;
        int bb = blockIdx.x - 768;
        int bR = bb % 192, bS = bb / 192;
        int r0 = bR * 64, s0 = bS * 64;
        int c4 = (tid & 15) * 4, rw = tid >> 4;   // rw 0..31
#pragma unroll
        for (int k = 0; k < 2; ++k) {
            int row = rw + 32 * k;
            float4 v = *(const float4*)&x[(size_t)(s0 + row) * 12288 + r0 + c4];
            tt[row][c4] = v.x; tt[row][c4 + 1] = v.y;
            tt[row][c4 + 2] = v.z; tt[row][c4 + 3] = v.w;
        }
        __syncthreads();
#pragma unroll
        for (int k = 0; k < 2; ++k) {
            int row = rw + 32 * k;
            float4 v = {tt[c4][row], tt[c4 + 1][row], tt[c4 + 2][row], tt[c4 + 3][row]};
            *(float4*)&xT[(size_t)(r0 + row) * 1024 + s0 + c4] = v;
        }
        return;
    }

    f2* a = (f2*)smem;                          // 32768 B
    float* row0 = (float*)(smem + 32768);       // [t][nh][c]  2048 B
    float* col0 = (float*)(smem + 34816);       // [t>>1][nh][r] 1024 B
    int d = blockIdx.x;
    int w = tid >> 6;
    int t = w & 3;
    int nh = w >> 2;
    int lane = tid & 63;
    int jg = lane & 7;
    int n8 = lane >> 3;
    int n = n8 + 8 * nh;
    int ch = t * 768 + d;
    int gid = ch * 16 + n;

    for (int e = tid; e < 4096; e += 512) a[e] = (f2){0.f, 0.f};
    row0[tid] = 0.f;
    if (tid < 256) col0[tid] = 0.f;

    f2 A[4];
#pragma unroll
    for (int q = 0; q < 4; ++q) {
        float ang = sigm(Aang[q * 49152 + gid]) * TWO_PI;
        float rad = sigm(Arad[q * 49152 + gid]);
        float s, co;
        __sincosf(ang, &s, &co);
        A[q] = (f2){rad * co, rad * s};
    }
    f2 A1 = A[0], A2 = A[1], A3 = A[2], A4 = A[3];
    f2 P2 = cms(A1, A1);
    f2 P3 = cms(A1, P2);
    f2 P4 = cms(P2, P2);
    f2 P8 = cms(P4, P4);
    f2 P16 = cms(P8, P8);
    f2 CZ1 = (jg >= 1) ? P4 : (f2){0.f, 0.f};
    f2 CZ2 = (jg >= 2) ? P8 : (f2){0.f, 0.f};
    f2 CZ4 = (jg >= 4) ? P16 : (f2){0.f, 0.f};

    const float2* B1v = (const float2*)B1p;
    const float2* B2v = (const float2*)B2p;
    const float2* C1v = (const float2*)C1p;
    const float2* C2v = (const float2*)C2p;
    float2 b1 = B1v[gid], b2 = B2v[gid], c1 = C1v[gid], c2 = C2v[gid];
    f2 B1 = (f2){sigm(b1.x), sigm(b1.y)};
    f2 B2 = (f2){sigm(b2.x), sigm(b2.y)};
    f2 C1n = (f2){c1.x, -c1.y};
    f2 C2n = (f2){c2.x, -c2.y};

    // EB = A1^{4*jg} * B1
    f2 pw = (f2){1.f, 0.f};
    if (jg & 1) pw = P4;
    if (jg & 2) pw = cms(pw, P8);
    if (jg & 4) pw = cms(pw, P16);
    f2 EB = cms(pw, B1);

    int bb0 = n8 & 1, bb1 = (n8 >> 1) & 1;
    int col = 4 * jg + 2 * bb0 + bb1;
    int ccl = (t & 2) ? ((64 - col) & 63) : col;

    __syncthreads();

    f2 xv[4], xh[4];
#pragma unroll
    for (int m = 0; m < 4; ++m) { xv[m] = (f2){0.f, 0.f}; xh[m] = (f2){0.f, 0.f}; }

    auto body = [&](int i, bool is0) {
#pragma unroll
        for (int m = 0; m < 4; ++m) xv[m] = cms(A3, xh[m]) + cms(A4, xv[m]);
        if (is0 && jg == 0) xv[0] += B2;
        f2 g1 = cms(A2, xv[0]);
        f2 g2 = cms(A1, g1) + cms(A2, xv[1]);
        f2 g3 = cms(A1, g2) + cms(A2, xv[2]);
        f2 V  = cms(A1, g3) + cms(A2, xv[3]);
        V += cms(CZ1, dpp2<DPP_SHR1>(V));
        V += cms(CZ2, dpp2<DPP_SHR2>(V));
        V += cms(CZ4, dpp2<DPP_SHR4>(V));
        f2 E = dpp2<DPP_SHR1>(V);
        if (jg == 0) E = (f2){0.f, 0.f};
        if (is0) E += EB;
        xh[0] = E;
        xh[1] = cms(A1, E) + g1;
        xh[2] = cms(P2, E) + g2;
        xh[3] = cms(P3, E) + g3;
        f2 d0 = C1n * xh[0] + C2n * xv[0];
        f2 d1 = C1n * xh[1] + C2n * xv[1];
        f2 d2 = C1n * xh[2] + C2n * xv[2];
        f2 d3 = C1n * xh[3] + C2n * xv[3];
        float v0 = d0.x + d0.y, v1 = d1.x + d1.y;
        float v2 = d2.x + d2.y, v3 = d3.x + d3.y;
        float s0 = bb0 ? v0 : v2, s1 = bb0 ? v1 : v3;
        float r0 = dpp0<DPP_ROR8>(s0), r1 = dpp0<DPP_ROR8>(s1);
        float q0 = (bb0 ? v2 : v0) + r0;
        float q1 = (bb0 ? v3 : v1) + r1;
        float s2 = bb1 ? q0 : q1;
        float r2 = swz_xor16(s2);
        float qq = (bb1 ? q1 : q0) + r2;
        qq += __shfl_xor(qq, 32, 64);
        if (n8 < 4) {
            if (is0) {
                row0[(((t << 1) | nh) << 6) | ccl] = qq;
            } else if (col == 0) {
                col0[((((t >> 1) << 1) | nh) << 6) | ((t & 1) ? (64 - i) : i)] = qq;
            } else {
                int rr_ = (t & 1) ? (64 - i) : i;
                ((float*)&a[swz(rr_, ccl)])[nh] = qq;
            }
        }
    };
    body(0, true);
#pragma unroll 2
    for (int i = 1; i < 32; ++i) body(i, false);

    __syncthreads();
    // fold: combine nh components + edge buffers, apply boundary factors
    for (int e = tid; e < 4096; e += 512) {
        int r = e >> 6, cm = e & 63;
        int c = cm ^ ((r ^ (r << 3)) & 63);
        f2 cv = a[e];
        float v = cv.x + cv.y;
        if (r == 0) {
            v += row0[c] + row0[64 + c] + row0[128 + c] + row0[192 + c]
               + row0[256 + c] + row0[320 + c] + row0[384 + c] + row0[448 + c];
        } else if (c == 0) {
            v += col0[r] + col0[64 + r] + col0[128 + r] + col0[192 + r];
        }
        float f = 0.25f;
        if (r == 0) f *= 2.f;
        if (c == 0) f *= 2.f;
        if (r == 0 && c == 0) f *= 0.25f;
        a[e] = (f2){f * v, 0.f};
    }
    __syncthreads();
    // 2D forward FFT -> Gf (single sweeps, 64 groups)
    int o = tid & 7;
    f2 tw[7];
    make_tw(o, tw);
    {
        int row = tid >> 3;
        f2 r[8];
#pragma unroll
        for (int j = 0; j < 8; ++j) r[j] = a[swz(row, 8 * j + o)];
        fft64<false, false, false, false>(a, r, tw, o, row);
#pragma unroll
        for (int m = 0; m < 8; ++m) a[swz(row, o + 8 * m)] = r[m];
    }
    __syncthreads();
    {
        int cc = tid >> 3;
        f2 r[8];
#pragma unroll
        for (int j = 0; j < 8; ++j) r[j] = a[swz(8 * j + o, cc)];
        fft64<false, true, false, false>(a, r, tw, o, cc);
        f2* GfD = Gf + d * 4096;
#pragma unroll
        for (int m = 0; m < 8; ++m) GfD[gfx2(o, m, cc)] = r[m];   // 64B contiguous
    }
}

// ---------------- P3: FFT conv, one b-pair tile, 512 thr (R12 winner) ---------
// xsave: epilogue x values == prologue values (cols 8j+o == o+8m) -> no re-read.
__global__ __launch_bounds__(512) void conv_fft(
        const float* __restrict__ x, float* __restrict__ xT,
        const f2* __restrict__ Gf, const float* __restrict__ omega,
        float* __restrict__ out, int useT) {
    __shared__ f2 a[4096];
    // XCD-chunked swizzle: same-d blocks (8 bpairs) colocate on one XCD.
    int bid = (blockIdx.x & 7) * 768 + (blockIdx.x >> 3);
    int d = bid >> 3, b = (bid & 7) * 2;
    int tid = threadIdx.x;
    int o = tid & 7, grp = tid >> 3;      // grp 0..63
    f2 tw[7];
    make_tw(o, tw);
    const size_t base0 = (size_t)(b * 768 + d) * 1024;
    const size_t base1 = (size_t)((b + 1) * 768 + d) * 1024;
    f2 xsave[4];
    // ---- forward rows (32 nonzero rows; groups 32..63 idle) ----
    if (grp < 32) {
        int row = grp;
        f2 r[8];
#pragma unroll
        for (int j = 0; j < 4; ++j) {
            int s2 = row * 32 + 8 * j + o;
            if (useT) r[j] = (f2){xT[base0 + s2], xT[base1 + s2]};
            else      r[j] = (f2){x[s2 * 12288 + b * 768 + d],
                                  x[s2 * 12288 + (b + 1) * 768 + d]};
            xsave[j] = r[j];
        }
#pragma unroll
        for (int j = 4; j < 8; ++j) r[j] = (f2){0.f, 0.f};
        fft64<false, false, true, false>(a, r, tw, o, row);
#pragma unroll
        for (int m = 0; m < 8; ++m) a[swz(row, o + 8 * m)] = r[m];
    }
    __syncthreads();
    // ---- columns (all 64 groups): fwd FFT ⊙ Gf, inv FFT in registers ----
    {
        int c = grp;
        const f2* GfD = Gf + d * 4096;
        f2 r[8];
#pragma unroll
        for (int j = 0; j < 4; ++j) r[j] = a[swz(8 * j + o, c)];
#pragma unroll
        for (int j = 4; j < 8; ++j) r[j] = (f2){0.f, 0.f};
        fft64<false, true, true, false>(a, r, tw, o, c);
#pragma unroll
        for (int m = 0; m < 8; ++m) {
            r[m] = cmulf(r[m], GfD[gfx2(o, m, c)]);   // 64B contiguous/thread
        }
        fft64<true, true, false, true>(a, r, tw, o, c);
#pragma unroll
        for (int m = 0; m < 4; ++m) a[swz(o + 8 * m, c)] = r[m];
    }
    __syncthreads();
    // ---- inverse rows + epilogue (groups 32..63 idle) ----
    if (grp < 32) {
        int row = grp;
        f2 r[8];
#pragma unroll
        for (int j = 0; j < 8; ++j) r[j] = a[swz(row, 8 * j + o)];
        fft64<true, false, false, true>(a, r, tw, o, row);
        float w = omega[d];
        const float inv = 1.0f / 4096.0f;
#pragma unroll
        for (int m = 0; m < 4; ++m) {
            int cc = o + 8 * m;
            int s2 = row * 32 + cc;
            float xa = xsave[m].x, xb = xsave[m].y;   // cols 8m+o == o+8m
            float ya = r[m].x * inv + xa * w;
            float yb = r[m].y * inv + xb * w;
            float oa = ya / (1.0f + __expf(-ya));
            float ob = yb / (1.0f + __expf(-yb));
            if (useT) {
                xT[base0 + s2] = oa;        // overwrite own row (outT alias)
                xT[base1 + s2] = ob;
            } else {
                out[s2 * 12288 + b * 768 + d] = oa;
                out[s2 * 12288 + (b + 1) * 768 + d] = ob;
            }
        }
    }
}

// ---------------- P4: xT (BD,S) -> out (S,BD), 64x64 tiles, float4 ------------
__global__ __launch_bounds__(256) void transpose_out(const float* __restrict__ xT,
                                                     float* __restrict__ out) {
    __shared__ float t[64][65];
    int bR = blockIdx.x % 192, bS = blockIdx.x / 192;
    int r0 = bR * 64, s0 = bS * 64;
    int c4 = (threadIdx.x & 15) * 4, rw = threadIdx.x >> 4;   // rw 0..15
#pragma unroll
    for (int k = 0; k < 4; ++k) {
        int row = rw + 16 * k;
        float4 v = *(const float4*)&xT[(size_t)(r0 + row) * 1024 + s0 + c4];
        t[row][c4] = v.x; t[row][c4 + 1] = v.y;
        t[row][c4 + 2] = v.z; t[row][c4 + 3] = v.w;
    }
    __syncthreads();
#pragma unroll
    for (int k = 0; k < 4; ++k) {
        int row = rw + 16 * k;
        float4 v = {t[c4][row], t[c4 + 1][row], t[c4 + 2][row], t[c4 + 3][row]};
        *(float4*)&out[(size_t)(s0 + row) * 12288 + r0 + c4] = v;
    }
}

extern "C" void kernel_launch(void* const* d_in, const int* in_sizes, int n_in,
                              void* d_out, int out_size, void* d_ws, size_t ws_size,
                              hipStream_t stream) {
    const float* x     = (const float*)d_in[0];
    const float* Aang  = (const float*)d_in[1];
    const float* Arad  = (const float*)d_in[2];
    const float* B1p   = (const float*)d_in[3];
    const float* B2p   = (const float*)d_in[4];
    const float* C1p   = (const float*)d_in[5];
    const float* C2p   = (const float*)d_in[6];
    const float* omega = (const float*)d_in[7];
    float* out = (float*)d_out;
    char* ws = (char*)d_ws;

    f2*    Gf = (f2*)ws;                            // 25,165,824 B
    float* xT = (float*)(ws + 25165824);            // 50,331,648 B (in+out alias)
    int useT = (ws_size >= (size_t)75497472) ? 1 : 0;

    int grid1 = useT ? 3840 : 768;   // 768 ssm blocks + 3072 transpose blocks
    ssm_tin<<<grid1, 512, 0, stream>>>(Aang, Arad, B1p, B2p, C1p, C2p, Gf, x, xT);
    conv_fft<<<6144, 512, 0, stream>>>(x, xT, Gf, omega, out, useT);
    if (useT) transpose_out<<<3072, 256, 0, stream>>>(xT, out);
}